// Round 3
// baseline (2468.018 us; speedup 1.0000x reference)
//
#include <hip/hip_runtime.h>

#define B_TOT   512
#define T_LEN   512
#define F_IN_D  8
#define H_DIM   128
#define OUT_DIM 7
#define TC      16                // timesteps per chunk = MFMA cols in prologue
#define NCHUNK  (T_LEN / TC)      // 32
#define NBLK    B_TOT             // BB=1 -> 512 blocks -> 2 blocks/CU
#define NTHREADS 512              // 8 waves

typedef __bf16 bf16x8 __attribute__((ext_vector_type(8)));
typedef float  f32x4  __attribute__((ext_vector_type(4)));

// Gate-row permutation: MFMA row p corresponds to original W row
// orig(p) = 128*(p&3) + (p>>2)  => acc[i][r] = gate r (i,f,g,o) of j=4*(mt)+q.
__device__ __forceinline__ int orig_row(int p) { return ((p & 3) << 7) | (p >> 2); }

struct __align__(16) SharedMem {
  float  xg[TC][H_DIM][4];   // [s][j][gate], bias included  (32 KB)
  float  gw[H_DIM][4];       // [j][gate] W_hh*h this step; wave-private j sets (2 KB)
  float  bias[H_DIM][4];     // [j][gate] b_ih+b_hh (2 KB)
  float  z[H_DIM];           // fc1 out
  __bf16 h[2][H_DIM];        // double-buffered hidden state (512 B)
  __bf16 hist[TC][H_DIM];    // per-chunk h history -> coalesced buf store (4 KB)
};

__device__ __forceinline__ float sigf(float x) {
  return __builtin_amdgcn_rcpf(1.f + __expf(-x));
}
__device__ __forceinline__ float tanh_fast(float x) {
  x = fminf(fmaxf(x, -15.f), 15.f);
  float e = __expf(2.f * x);
  return (e - 1.f) * __builtin_amdgcn_rcpf(e + 1.f);
}
__device__ __forceinline__ bf16x8 load8_f32_bf16(const float* p) {
  const f32x4 a = *(const f32x4*)p;
  const f32x4 b = *(const f32x4*)(p + 4);
  bf16x8 r;
  #pragma unroll
  for (int j = 0; j < 4; ++j) { r[j] = (__bf16)a[j]; r[4 + j] = (__bf16)b[j]; }
  return r;
}
__device__ __forceinline__ bf16x8 zero_bf16x8() {
  bf16x8 r;
  #pragma unroll
  for (int j = 0; j < 8; ++j) r[j] = (__bf16)0.f;
  return r;
}

__global__ __launch_bounds__(NTHREADS, 4)   // 4 waves/SIMD -> 2 blocks/CU
void lstm_kernel(const float* __restrict__ x,
                 const float* __restrict__ wih0, const float* __restrict__ whh0,
                 const float* __restrict__ bih0, const float* __restrict__ bhh0,
                 const float* __restrict__ wih1, const float* __restrict__ whh1,
                 const float* __restrict__ bih1, const float* __restrict__ bhh1,
                 const float* __restrict__ wih2, const float* __restrict__ whh2,
                 const float* __restrict__ bih2, const float* __restrict__ bhh2,
                 const float* __restrict__ fc1w, const float* __restrict__ fc1b,
                 const float* __restrict__ fc2w, const float* __restrict__ fc2b,
                 float* __restrict__ out, __bf16* __restrict__ buf)
{
  __shared__ SharedMem sh;
  const int tid = threadIdx.x;
  const int w   = tid >> 6;   // wave 0..7
  const int l   = tid & 63;   // lane
  const int q   = l >> 4;     // quad 0..3
  const int n16 = l & 15;     // MFMA col / A-row-within-tile
  const int bg  = blockIdx.x; // one batch row per block

  const float* WIH[3] = {wih0, wih1, wih2};
  const float* WHH[3] = {whh0, whh1, whh2};
  const float* BIH[3] = {bih0, bih1, bih2};
  const float* BHH[3] = {bhh0, bhh1, bhh2};

  for (int lyr = 0; lyr < 3; ++lyr) {
    const float* w_ih = WIH[lyr];
    const float* w_hh = WHH[lyr];
    const int kin        = (lyr == 0) ? F_IN_D : H_DIM;
    const int kin_chunks = (lyr == 0) ? 1 : 4;

    // ---- per-layer resident W_hh A-fragments (permuted rows) ----
    bf16x8 whhf[4][4];   // [tile][kchunk] = 64 VGPRs
    #pragma unroll
    for (int i = 0; i < 4; ++i) {
      const int row = orig_row(16 * (w + 8 * i) + n16);
      #pragma unroll
      for (int kc = 0; kc < 4; ++kc)
        whhf[i][kc] = load8_f32_bf16(w_hh + row * H_DIM + kc * 32 + q * 8);
    }
    // bias staged in LDS: bias[j][g]
    {
      const int j = tid >> 2, g = tid & 3;
      sh.bias[j][g] = BIH[lyr][(g << 7) + j] + BHH[lyr][(g << 7) + j];
    }
    if (tid < H_DIM) sh.h[0][tid] = (__bf16)0.f;
    float c_st = 0.f;          // cell state (lanes l<16 hold real values)
    __syncthreads();           // h reset + bias visible; drains prev-layer buf stores

    for (int c0 = 0; c0 < NCHUNK; ++c0) {
      const int t0 = c0 * TC;

      // ---- prologue: xg for TC=16 steps (col n16 = step) ----
      {
        f32x4 acc[4];
        #pragma unroll
        for (int i = 0; i < 4; ++i)
          acc[i] = *(const f32x4*)&sh.bias[4 * (w + 8 * i) + q][0];
        const int t = t0 + n16;
        for (int kc = 0; kc < kin_chunks; ++kc) {   // wave-uniform trip count
          bf16x8 bfrag;
          if (lyr == 0) {
            bfrag = zero_bf16x8();
            if (q == 0)
              bfrag = load8_f32_bf16(x + ((size_t)bg * T_LEN + t) * F_IN_D);
          } else {
            bfrag = *(const bf16x8*)(buf + ((size_t)bg * T_LEN + t) * H_DIM
                                         + kc * 32 + q * 8);
          }
          bf16x8 wf[4];
          #pragma unroll
          for (int i = 0; i < 4; ++i) {
            const int row = orig_row(16 * (w + 8 * i) + n16);
            const int k0  = kc * 32 + q * 8;
            wf[i] = (k0 < kin) ? load8_f32_bf16(w_ih + row * kin + k0)
                               : zero_bf16x8();
          }
          #pragma unroll
          for (int i = 0; i < 4; ++i)
            acc[i] = __builtin_amdgcn_mfma_f32_16x16x32_bf16(wf[i], bfrag, acc[i], 0, 0, 0);
        }
        #pragma unroll
        for (int i = 0; i < 4; ++i)
          *(f32x4*)&sh.xg[n16][4 * (w + 8 * i) + q][0] = acc[i];
      }
      __syncthreads();

      // ---- TC recurrence steps, ONE barrier each ----
      for (int s = 0; s < TC; ++s) {
        const int cur = s & 1;     // t0 even -> t parity == s parity
        const int nxt = cur ^ 1;

        f32x4 acc[4];
        #pragma unroll
        for (int i = 0; i < 4; ++i) { f32x4 zv = {0.f,0.f,0.f,0.f}; acc[i] = zv; }
        #pragma unroll
        for (int kc = 0; kc < 4; ++kc) {
          const bf16x8 bfrag = *(const bf16x8*)&sh.h[cur][kc * 32 + q * 8]; // broadcast
          #pragma unroll
          for (int i = 0; i < 4; ++i)
            acc[i] = __builtin_amdgcn_mfma_f32_16x16x32_bf16(whhf[i][kc], bfrag, acc[i], 0, 0, 0);
        }
        // col 0 holds the real batch row; acc[i] = 4 gates of j=4*(w+8i)+q
        if (n16 == 0) {
          #pragma unroll
          for (int i = 0; i < 4; ++i)
            *(f32x4*)&sh.gw[4 * (w + 8 * i) + q][0] = acc[i];
        }
        __builtin_amdgcn_wave_barrier();   // wave-local LDS RT; lgkmcnt orders it
        if (l < 16) {                      // 16 dense gate lanes per wave
          const int j = 4 * w + (l & 3) + 32 * (l >> 2);
          const f32x4 gv = *(const f32x4*)&sh.gw[j][0];
          const f32x4 xv = *(const f32x4*)&sh.xg[s][j][0];
          const float gi = gv[0] + xv[0], gf = gv[1] + xv[1];
          const float gg = gv[2] + xv[2], go = gv[3] + xv[3];
          c_st = sigf(gf) * c_st + sigf(gi) * tanh_fast(gg);
          const __bf16 hb = (__bf16)(sigf(go) * tanh_fast(c_st));
          sh.h[nxt][j]   = hb;
          sh.hist[s][j]  = hb;
        }
        __syncthreads();
      }

      // ---- chunk epilogue: coalesced hist -> buf (no per-step vmcnt drain) ----
      if (lyr < 2) {
        const int s2 = tid >> 5, j4 = (tid & 31) * 4;
        const uint2 v = *(const uint2*)&sh.hist[s2][j4];
        *(uint2*)(buf + ((size_t)bg * T_LEN + t0 + s2) * H_DIM + j4) = v;
      }
      // stores drain at next chunk's post-prologue barrier (overlapped)
    }
  }

  // ---- FC head: final h (t=511 wrote parity 0) ----
  if (tid < H_DIM) {
    float a = fc1b[tid];
    #pragma unroll 8
    for (int k = 0; k < H_DIM; ++k)
      a += (float)sh.h[0][k] * fc1w[tid * H_DIM + k];
    sh.z[tid] = fmaxf(a, 0.f);
  }
  __syncthreads();
  if (tid < OUT_DIM) {
    float a = fc2b[tid];
    for (int k = 0; k < H_DIM; ++k)
      a += sh.z[k] * fc2w[tid * H_DIM + k];
    out[(size_t)bg * OUT_DIM + tid] = a;
  }
}

extern "C" void kernel_launch(void* const* d_in, const int* in_sizes, int n_in,
                              void* d_out, int out_size, void* d_ws, size_t ws_size,
                              hipStream_t stream) {
  const float* x    = (const float*)d_in[0];
  const float* wih0 = (const float*)d_in[1];
  const float* whh0 = (const float*)d_in[2];
  const float* bih0 = (const float*)d_in[3];
  const float* bhh0 = (const float*)d_in[4];
  const float* wih1 = (const float*)d_in[5];
  const float* whh1 = (const float*)d_in[6];
  const float* bih1 = (const float*)d_in[7];
  const float* bhh1 = (const float*)d_in[8];
  const float* wih2 = (const float*)d_in[9];
  const float* whh2 = (const float*)d_in[10];
  const float* bih2 = (const float*)d_in[11];
  const float* bhh2 = (const float*)d_in[12];
  const float* fc1w = (const float*)d_in[13];
  const float* fc1b = (const float*)d_in[14];
  const float* fc2w = (const float*)d_in[15];
  const float* fc2b = (const float*)d_in[16];
  float* out  = (float*)d_out;
  __bf16* buf = (__bf16*)d_ws;   // [512][512][128] bf16 = 64 MiB inter-layer buffer

  lstm_kernel<<<dim3(NBLK), dim3(NTHREADS), 0, stream>>>(
      x, wih0, whh0, bih0, bhh0, wih1, whh1, bih1, bhh1,
      wih2, whh2, bih2, bhh2, fc1w, fc1b, fc2w, fc2b, out, buf);
}